// Round 3
// baseline (151.337 us; speedup 1.0000x reference)
//
#include <hip/hip_runtime.h>
#include <stdint.h>
#include <math.h>

#define B_ 16
#define T_ 512
#define C_ 3
#define V_ 16
#define H_ 128
#define NC_ 12

typedef float v2f __attribute__((ext_vector_type(2)));

// workspace layout (float offsets)
#define WS_W2P   0        // 16384: w2 pair-interleaved: [o][l] = (w2[l][o], w2[l+64][o])
#define WS_INV1  16384    // 128
#define WS_D1    16512    // 128
#define WS_INV2  16640    // 128
#define WS_D2    16768    // 128
#define WS_FEAT  16896    // 2048: per-(b,h) spike totals
// total 18944 floats = 75776 bytes

__global__ void prep_kernel(const float* __restrict__ w2,
                            const float* __restrict__ g1, const float* __restrict__ be1,
                            const float* __restrict__ m1, const float* __restrict__ rv1,
                            const float* __restrict__ g2, const float* __restrict__ be2,
                            const float* __restrict__ m2, const float* __restrict__ rv2,
                            float* __restrict__ ws) {
    int i = blockIdx.x * blockDim.x + threadIdx.x;
    if (i < H_ * H_) {
        // pair-interleaved transpose: ws[o*128 + 2*l + h] = w2[(l + 64*h)*128 + o]
        int o = i >> 7, j = i & (H_ - 1);
        int l = j >> 1, hh = j & 1;
        ws[WS_W2P + i] = w2[(l + 64 * hh) * H_ + o];
    } else if (i >= H_ * H_ && i < H_ * H_ + B_ * H_) {
        ws[WS_FEAT + (i - H_ * H_)] = 0.0f;   // zero feat accumulators
    }
    if (i < H_) {
        float r1 = (float)(1.0 / sqrt((double)(rv1[i] + 1e-5f)));
        float inv1 = g1[i] * r1;
        ws[WS_INV1 + i] = inv1;
        ws[WS_D1 + i] = be1[i] - m1[i] * inv1;
        float r2 = (float)(1.0 / sqrt((double)(rv2[i] + 1e-5f)));
        float inv2 = g2[i] * r2;
        ws[WS_INV2 + i] = inv2;
        ws[WS_D2 + i] = be2[i] - m2[i] * inv2;
    }
}

// One wave per site; lane l owns channels l and l+64 (adjacent in paired LDS layout).
// Block = 1024 threads = 16 waves; each block covers 128 sites of one batch b.
__global__ __launch_bounds__(1024) void snn_main(
    const float* __restrict__ x,
    const float* __restrict__ w1, const float* __restrict__ b1,
    const float* __restrict__ b2, const float* __restrict__ ws,
    float* __restrict__ feat)
{
    __shared__ float smem[H_ * H_];   // paired w2 during loop; reduction buffer after

    const int tid  = threadIdx.x;
    const int lane = tid & 63;
    const int wave = tid >> 6;        // 0..15

    // stage paired w2 (64KB) into LDS, coalesced float4
    {
        const float4* src = (const float4*)(ws + WS_W2P);
        float4* dst = (float4*)smem;
        #pragma unroll
        for (int i = 0; i < 4; ++i) dst[tid + i * 1024] = src[tid + i * 1024];
    }

    const int p = lane;        // channel A
    const int q = lane + 64;   // channel B

    // per-channel-pair constants as packed v2f (L1-cached broadcasts)
    v2f w0v = { w1[p*3+0], w1[q*3+0] };
    v2f w1v = { w1[p*3+1], w1[q*3+1] };
    v2f w2v = { w1[p*3+2], w1[q*3+2] };
    v2f b1v = { b1[p], b1[q] };
    v2f i1v = { ws[WS_INV1+p], ws[WS_INV1+q] };
    v2f d1v = { ws[WS_D1+p],  ws[WS_D1+q] };
    v2f b2v = { b2[p], b2[q] };
    v2f i2v = { ws[WS_INV2+p], ws[WS_INV2+q] };
    v2f d2v = { ws[WS_D2+p],  ws[WS_D2+q] };

    const int b     = blockIdx.x >> 6;   // 64 blocks per batch
    const int chunk = blockIdx.x & 63;

    // per-lane base pointers into paired rows: row o (channels) at v2f index o*64 + lane
    const v2f* wrowL = ((const v2f*)smem) + lane;           // source channels 0..63
    const v2f* wrowH = wrowL + 64 * 64;                     // source channels 64..127

    v2f facc = { 0.f, 0.f };

    __syncthreads();

    // t = chunk*8 + it, v = wave; x[b, t, c, v]
    const float* xp = x + (((size_t)b * T_ + (size_t)chunk * 8) * C_) * V_ + wave;

    for (int it = 0; it < 8; ++it, xp += C_ * V_) {
        float x0 = xp[0], x1 = xp[V_], x2 = xp[2 * V_];   // wave-uniform

        // fc1 + BN1, reference rounding order (pk ops)
        v2f h1 = ((x0 * w0v + x1 * w1v + x2 * w2v) + b1v) * i1v + d1v;

        // LIF1 closed form: unreset trajectory (exact reference rounding).
        // v1t = h/2 (exact), v2t = fl(3h/4), v3t/v4t one rounding each —
        // identical to the step simulation with hard reset (post-reset
        // states revisit this prefix). First spike step k <-> nested
        // threshold crossings of the monotone trajectory.
        v2f v1t = h1 * 0.5f;
        v2f v2t = v1t + h1 * 0.25f;
        v2f d3  = h1 - v2t;
        v2f v3t = v2t + d3 * 0.5f;
        v2f d4  = h1 - v3t;
        v2f v4t = v3t + d4 * 0.5f;

        unsigned long long t1a = __ballot(v1t.x >= 0.5f);
        unsigned long long t2a = __ballot(v2t.x >= 0.5f);
        unsigned long long t3a = __ballot(v3t.x >= 0.5f);
        unsigned long long t4a = __ballot(v4t.x >= 0.5f);
        unsigned long long t1b = __ballot(v1t.y >= 0.5f);
        unsigned long long t2b = __ballot(v2t.y >= 0.5f);
        unsigned long long t3b = __ballot(v3t.y >= 0.5f);
        unsigned long long t4b = __ballot(v4t.y >= 0.5f);

        // class masks: A = first spike step1, B = step2, C = step3, D = step4
        unsigned long long mA0 = t1a,         mA1 = t1b;
        unsigned long long mB0 = t2a & ~t1a,  mB1 = t2b & ~t1b;
        unsigned long long mC0 = t3a & ~t2a,  mC1 = t3b & ~t2b;
        unsigned long long mD0 = t4a & ~t3a,  mD1 = t4b & ~t3b;

        v2f SA = {0.f,0.f}, SB = {0.f,0.f}, SC = {0.f,0.f}, SD = {0.f,0.f};

        // 2-bit unrolled walk: two independent ds_read_b64 in flight per iter
        #define ACC(mask, base, S)                                  \
            { unsigned long long m = (mask);                        \
              v2f Sx = {0.f, 0.f};                                  \
              while (m) {                                           \
                  int o0 = __builtin_ctzll(m); m &= m - 1;          \
                  if (m) {                                          \
                      int o1 = __builtin_ctzll(m); m &= m - 1;      \
                      v2f wv0 = (base)[o0 << 6];                    \
                      v2f wv1 = (base)[o1 << 6];                    \
                      S  += wv0;                                    \
                      Sx += wv1;                                    \
                  } else {                                          \
                      S += (base)[o0 << 6];                         \
                  }                                                 \
              }                                                     \
              S += Sx; }

        ACC(mA0, wrowL, SA) ACC(mA1, wrowH, SA)
        ACC(mB0, wrowL, SB) ACC(mB1, wrowH, SB)
        ACC(mC0, wrowL, SC) ACC(mC1, wrowH, SC)
        ACC(mD0, wrowL, SD) ACC(mD1, wrowH, SD)
        #undef ACC

        // per-step raw dots: step1=SA, step2=SA+SB, step3=SA+SC, step4=SA+SB+SD
        v2f r1 = SA, r2 = SA + SB, r3 = SA + SC, r4 = r2 + SD;

        v2f h2s[4] = { (r1 + b2v) * i2v + d2v, (r2 + b2v) * i2v + d2v,
                       (r3 + b2v) * i2v + d2v, (r4 + b2v) * i2v + d2v };

        // LIF2, exact reference rounding (packed)
        v2f v = { 0.f, 0.f };
        #pragma unroll
        for (int s = 0; s < 4; ++s) {
            v2f d = h2s[s] - v;
            v = v + d * 0.5f;
            bool sx = v.x >= 0.5f;
            bool sy = v.y >= 0.5f;
            v.x = sx ? 0.f : v.x;
            v.y = sy ? 0.f : v.y;
            facc.x += sx ? 1.f : 0.f;
            facc.y += sy ? 1.f : 0.f;
        }
    }

    // block reduction (reuse smem; all partial sums are exact small integers)
    __syncthreads();
    smem[wave * H_ + p] = facc.x;
    smem[wave * H_ + q] = facc.y;
    __syncthreads();
    if (wave == 0) {
        float sa = 0.f, sb = 0.f;
        #pragma unroll
        for (int w = 0; w < 16; ++w) { sa += smem[w * H_ + p]; sb += smem[w * H_ + q]; }
        atomicAdd(&feat[b * H_ + p], sa);
        atomicAdd(&feat[b * H_ + q], sb);
    }
}

// one wave per (b, n) output element
__global__ __launch_bounds__(64) void classifier_kernel(
    const float* __restrict__ feat,
    const float* __restrict__ wc,
    const float* __restrict__ bc,
    float* __restrict__ out) {
    int bn = blockIdx.x;
    int b = bn / NC_, n = bn % NC_;
    int l = threadIdx.x;
    const float sc = 1.0f / 32768.0f;   // 1/(S*T*V), exact pow2
    float2 f = *(const float2*)(feat + b * H_ + 2 * l);
    float2 w = *(const float2*)(wc + n * H_ + 2 * l);
    float s = (f.x * sc) * w.x + (f.y * sc) * w.y;
    #pragma unroll
    for (int off = 32; off > 0; off >>= 1) s += __shfl_down(s, off);
    if (l == 0) out[bn] = s + bc[n];
}

extern "C" void kernel_launch(void* const* d_in, const int* in_sizes, int n_in,
                              void* d_out, int out_size, void* d_ws, size_t ws_size,
                              hipStream_t stream) {
    const float* x   = (const float*)d_in[0];
    const float* w1  = (const float*)d_in[1];
    const float* b1  = (const float*)d_in[2];
    const float* g1  = (const float*)d_in[3];
    const float* be1 = (const float*)d_in[4];
    const float* m1  = (const float*)d_in[5];
    const float* rv1 = (const float*)d_in[6];
    const float* w2  = (const float*)d_in[7];
    const float* b2  = (const float*)d_in[8];
    const float* g2  = (const float*)d_in[9];
    const float* be2 = (const float*)d_in[10];
    const float* m2  = (const float*)d_in[11];
    const float* rv2 = (const float*)d_in[12];
    const float* wc  = (const float*)d_in[13];
    const float* bc  = (const float*)d_in[14];
    float* ws  = (float*)d_ws;
    float* out = (float*)d_out;

    // 80 blocks x 256 covers transpose (16384) + feat zero (2048)
    prep_kernel<<<80, 256, 0, stream>>>(w2, g1, be1, m1, rv1, g2, be2, m2, rv2, ws);
    snn_main<<<1024, 1024, 0, stream>>>(x, w1, b1, b2, ws, ws + WS_FEAT);
    classifier_kernel<<<B_ * NC_, 64, 0, stream>>>(ws + WS_FEAT, wc, bc, out);
}